// Round 10
// baseline (62128.387 us; speedup 1.0000x reference)
//
#include <hip/hip_runtime.h>

#define TT    8192
#define HD    1024
#define NBLK  256       // compute blocks; block NBLK = dedicated sequencer
#define NTHR  256
#define NBUF  4         // ring depth — mixed-path safety proof below
#define NREP  8         // flag replicas, one 64B line each
#define NXCD  8
#define L2_TRIES 64     // bounded fast-path poll (≈64 L2 hits ~ 16k cyc max)

typedef int i32x4 __attribute__((ext_vector_type(4)));
typedef int i32x2 __attribute__((ext_vector_type(2)));

// ---- LLC-coherent accesses (sc0 sc1 = bypass L1+L2, coherent at MALL) ----
__device__ __forceinline__ void llc_load_pair(const unsigned* p, i32x4& a, i32x4& b) {
  asm volatile("global_load_dwordx4 %0, %2, off sc0 sc1\n\t"
               "global_load_dwordx4 %1, %3, off sc0 sc1\n\t"
               "s_waitcnt vmcnt(0)"
               : "=&v"(a), "=&v"(b)
               : "v"(p), "v"(p + 4)
               : "memory");
}
__device__ __forceinline__ unsigned llc_load1(const unsigned* p) {
  unsigned r;
  asm volatile("global_load_dword %0, %1, off sc0 sc1\n\ts_waitcnt vmcnt(0)"
               : "=v"(r) : "v"(p) : "memory");
  return r;
}
__device__ __forceinline__ void llc_store2(unsigned* p, unsigned lo, unsigned hi) {
  i32x2 v; v.x = (int)lo; v.y = (int)hi;
  asm volatile("global_store_dwordx2 %0, %1, off sc0 sc1"
               :: "v"(p), "v"(v) : "memory");
}
__device__ __forceinline__ void llc_store1(unsigned* p, unsigned v) {
  asm volatile("global_store_dword %0, %1, off sc0 sc1"
               :: "v"(p), "v"(v) : "memory");
}
// ---- XCD-local (L2) accesses: sc0 load = bypass L1, hit shared L2;
// plain store = default scope, lands in this XCD's write-back L2.
__device__ __forceinline__ void l2_load_pair(const unsigned* p, i32x4& a, i32x4& b) {
  asm volatile("global_load_dwordx4 %0, %2, off sc0\n\t"
               "global_load_dwordx4 %1, %3, off sc0\n\t"
               "s_waitcnt vmcnt(0)"
               : "=&v"(a), "=&v"(b)
               : "v"(p), "v"(p + 4)
               : "memory");
}
__device__ __forceinline__ void l2_store4(unsigned* p, i32x4 v) {
  asm volatile("global_store_dwordx4 %0, %1, off"
               :: "v"(p), "v"(v) : "memory");
}

__device__ __forceinline__ float sigf(float z) {
  return 1.0f / (1.0f + __expf(-z));
}
__device__ __forceinline__ float tanh_fast(float z) {
  float az = fabsf(z);
  float e  = __expf(2.0f * az);          // >= 1
  float t  = 1.0f - 2.0f / (e + 1.0f);
  return z < 0.0f ? -t : t;
}

#define FMA4(acc, hvv, wvv)                                      \
  acc = fmaf((hvv).x, (wvv).x, acc);                             \
  acc = fmaf((hvv).y, (wvv).y, acc);                             \
  acc = fmaf((hvv).z, (wvv).z, acc);                             \
  acc = fmaf((hvv).w, (wvv).w, acc);

// hbuf: unsigned[NBUF][HD][2] {value_bits, tag}; h of step t -> slot t%NBUF,
// tag t+1.  xmirror: unsigned[NXCD][NBUF][HD][2] — per-XCD L2-local copy,
// written by that XCD's relay with PLAIN stores.  flag: NREP replicas,
// raised by the sequencer after verifying all 1024 tags (fallback cert).
// relay_slot[x]: CAS election; first block per XCD relays.
//
// MIXED-PATH RING SAFETY (NBUF=4): any producer stores h_{t+3} (overwriting
// slot (t-1)%4) only after consuming step t+2, which requires ALL 1024 tags
// of t+2 (either path verifies its block's full tag set before compute), so
// every block produced t+2, so every block consumed t+1, ... so every block
// consumed t, i.e. finished reading slot (t-1)%4.  A fallback consumer at
// step t gates the world the same way: until it produces h_t, nobody can
// consume t+1, so no overwrite of its source slot can happen.  The sequencer
// uses tag >= (not ==) so it can never wedge if fast-path blocks run ahead.
extern "C" __global__ __launch_bounds__(NTHR, 1)
void lstm_persistent(const float* __restrict__ x,
                     const float* __restrict__ W_ih,
                     const float* __restrict__ W_hh,
                     const float* __restrict__ b_ih,
                     const float* __restrict__ b_hh,
                     const float* __restrict__ W_fc,
                     const float* __restrict__ b_fc,
                     float* __restrict__ out,
                     int*      __restrict__ relay_slot,
                     unsigned* __restrict__ flag,
                     unsigned* __restrict__ hbuf,
                     unsigned* __restrict__ xmirror)
{
  const int tid = threadIdx.x;
  const int blk = blockIdx.x;

  // ================= block NBLK: dedicated sequencer (fallback cert) =====
  if (blk == NBLK) {
    for (int t = 0; t < TT; ++t) {
      const unsigned* src = hbuf + (((t & (NBUF - 1)) * HD + tid * 4) * 2);
      i32x4 A, B;
      const int want = t + 1;
      do {                                  // >= : slot tags only grow
        llc_load_pair(src, A, B);
      } while (!(A.y >= want && A.w >= want && B.y >= want && B.w >= want));
      __syncthreads();
      if (tid < NREP)
        llc_store1(flag + (tid << 4), (unsigned)want);
    }
    return;
  }

  // ================= blocks 0..255: compute ==============================
  __shared__ float x_lds[TT];     // 32 KB: whole input sequence
  __shared__ float h_lds[HD];     //  4 KB: broadcast of h_{t-1}
  __shared__ int   info_lds[2];   // [is_relay, xcd]

  const int wave = tid >> 6;
  const int lane = tid & 63;
  const int g    = lane >> 4;     // gate 0..3 (i,f,g,o)
  const int kc   = lane & 15;     // k-chunk within the 1024-dot
  const int unit = blk * 4 + wave;

  // ---- relay election (one-time) ---------------------------------------
  if (tid == 0) {
    int xcd;
    asm volatile("s_getreg_b32 %0, hwreg(HW_REG_XCC_ID)" : "=s"(xcd));
    xcd &= (NXCD - 1);
    int old = atomicCAS(&relay_slot[xcd], -1, blk);
    info_lds[0] = (old == -1) ? 1 : 0;
    info_lds[1] = xcd;
  }

  // ---- one-time staging -------------------------------------------------
  for (int i = tid; i < TT / 4; i += NTHR)
    ((float4*)x_lds)[i] = ((const float4*)x)[i];

  // W_hh row (gate g, unit) — lane covers k = m*64 + kc*4 + {0..3}
  float4 w4[16];
  {
    const float* wr = W_hh + (size_t)(g * HD + unit) * HD + kc * 4;
#pragma unroll
    for (int m = 0; m < 16; ++m)
      w4[m] = *((const float4*)(wr + m * 64));
  }
  float4 wfc4[4];
#pragma unroll
  for (int m = 0; m < 4; ++m)
    wfc4[m] = *((const float4*)(W_fc + m * 256 + lane * 4));
  const float bfc_val = b_fc[0];

  float wih_g[4], bs_g[4];
#pragma unroll
  for (int q = 0; q < 4; ++q) {
    int r = q * HD + unit;
    wih_g[q] = W_ih[r];
    bs_g[q]  = b_ih[r] + b_hh[r];
  }
  float c_state = 0.0f;
  __syncthreads();                // x_lds + info_lds ready

  const bool is_relay = (info_lds[0] != 0);
  const int  myx      = info_lds[1];
  const unsigned* flag_mine = flag + ((blk & (NREP - 1)) << 4);

  bool use_l2 = true;             // per-thread fast-path enable
  int  l2fail = 0;

  // ---- the sequential scan ---------------------------------------------
  for (int t = 0; t < TT; ++t) {
    const bool doproj = (t > 0) && (wave == 1) && (blk == (t & 255));
    float accs = 0.0f;
    float4 hp4[4];

    if (t > 0) {
      const int slot = (t - 1) & (NBUF - 1);
      float4 hv;
      bool got = false;
      i32x4 A, B;

      if (is_relay) {
        // poll producers at the MALL (self-gating: == cannot be skipped),
        // then forward own 32 B into this XCD's L2 mirror (fire & forget)
        const unsigned* src = hbuf + ((size_t)slot * HD + tid * 4) * 2;
        do {
          llc_load_pair(src, A, B);
        } while (!(A.y == t && A.w == t && B.y == t && B.w == t));
        unsigned* dst = xmirror + (((size_t)myx * NBUF + slot) * HD + tid * 4) * 2;
        l2_store4(dst, A);
        l2_store4(dst + 4, B);
        got = true;
      } else {
        if (use_l2) {
          // bounded tag-verified poll of the XCD-local mirror (L2 hits)
          const unsigned* msrc =
              xmirror + (((size_t)myx * NBUF + slot) * HD + tid * 4) * 2;
          for (int it = 0; it < L2_TRIES; ++it) {
            l2_load_pair(msrc, A, B);
            if (A.y == t && A.w == t && B.y == t && B.w == t) { got = true; break; }
          }
          if (got) l2fail = 0;
          else if (++l2fail >= 2) use_l2 = false;   // permanent fallback
        }
        if (!got) {
          // proven R9 path: certified flag + single-shot MALL read
          while (llc_load1(flag_mine) < (unsigned)t) { }
          const unsigned* src = hbuf + ((size_t)slot * HD + tid * 4) * 2;
          llc_load_pair(src, A, B);
        }
      }
      hv.x = __int_as_float(A.x); hv.y = __int_as_float(A.z);
      hv.z = __int_as_float(B.x); hv.w = __int_as_float(B.z);
      ((float4*)h_lds)[tid] = hv;
      __syncthreads();

      // fragments + 64 FMAs (4 independent sub-chains)
      const float* hp = h_lds + kc * 4;
      float s0 = 0.f, s1 = 0.f, s2 = 0.f, s3 = 0.f;
#pragma unroll
      for (int mb = 0; mb < 4; ++mb) {
        float4 ha = *((const float4*)(hp + (mb * 4 + 0) * 64));
        float4 hb = *((const float4*)(hp + (mb * 4 + 1) * 64));
        float4 hc = *((const float4*)(hp + (mb * 4 + 2) * 64));
        float4 hd = *((const float4*)(hp + (mb * 4 + 3) * 64));
        FMA4(s0, ha, w4[mb * 4 + 0]);
        FMA4(s1, hb, w4[mb * 4 + 1]);
        FMA4(s2, hc, w4[mb * 4 + 2]);
        FMA4(s3, hd, w4[mb * 4 + 3]);
      }
      accs = (s0 + s1) + (s2 + s3);

      if (doproj) {
#pragma unroll
        for (int m = 0; m < 4; ++m)
          hp4[m] = *((const float4*)(h_lds + m * 256 + lane * 4));
      }
    }

    // 4-round butterfly over kc: every lane in a gate-group gets the row sum
#pragma unroll
    for (int s = 1; s < 16; s <<= 1)
      accs += __shfl_xor(accs, s);

    float gi = __shfl(accs, 0);
    float gf = __shfl(accs, 16);
    float gg = __shfl(accs, 32);
    float go = __shfl(accs, 48);

    if (lane == 0) {
      float xt = x_lds[t];
      gi += fmaf(xt, wih_g[0], bs_g[0]);
      gf += fmaf(xt, wih_g[1], bs_g[1]);
      gg += fmaf(xt, wih_g[2], bs_g[2]);
      go += fmaf(xt, wih_g[3], bs_g[3]);
      c_state  = sigf(gf) * c_state + sigf(gi) * tanh_fast(gg);
      float hn = sigf(go) * tanh_fast(c_state);
      llc_store2(hbuf + (((t & (NBUF - 1)) * HD + unit) * 2),
                 __float_as_uint(hn), (unsigned)(t + 1));  // fire & forget
    }

    // fused output projection for step t-1 (register-only, off crit path)
    if (doproj) {
      float p = 0.f;
#pragma unroll
      for (int m = 0; m < 4; ++m) { FMA4(p, hp4[m], wfc4[m]); }
#pragma unroll
      for (int s = 1; s < 64; s <<= 1) p += __shfl_xor(p, s);
      if (lane == 0) out[t - 1] = p + bfc_val;
    }
  }

  // ---- epilogue: out[TT-1] by block 0 (tag-verified direct MALL read) ----
  if (blk == 0) {
    const unsigned* src = hbuf + (((TT - 1) & (NBUF - 1)) * HD + tid * 4) * 2;
    i32x4 A, B;
    do {
      llc_load_pair(src, A, B);
    } while (!(A.y == TT && A.w == TT && B.y == TT && B.w == TT));
    float4 hv;
    hv.x = __int_as_float(A.x); hv.y = __int_as_float(A.z);
    hv.z = __int_as_float(B.x); hv.w = __int_as_float(B.z);
    ((float4*)h_lds)[tid] = hv;
    __syncthreads();
    if (wave == 1) {
      float p = 0.f;
#pragma unroll
      for (int m = 0; m < 4; ++m) {
        float4 hm = *((const float4*)(h_lds + m * 256 + lane * 4));
        FMA4(p, hm, wfc4[m]);
      }
#pragma unroll
      for (int s = 1; s < 64; s <<= 1) p += __shfl_xor(p, s);
      if (lane == 0) out[TT - 1] = p + bfc_val;
    }
  }
}

extern "C" void kernel_launch(void* const* d_in, const int* in_sizes, int n_in,
                              void* d_out, int out_size, void* d_ws, size_t ws_size,
                              hipStream_t stream) {
  const float* x   = (const float*)d_in[0];
  const float* Wih = (const float*)d_in[1];
  const float* Whh = (const float*)d_in[2];
  const float* bih = (const float*)d_in[3];
  const float* bhh = (const float*)d_in[4];
  const float* Wfc = (const float*)d_in[5];
  const float* bfc = (const float*)d_in[6];
  float* out = (float*)d_out;

  // ws layout:
  //   +0    : relay_slot int[NXCD]         (memset 0xFF -> -1), pad to 256 B
  //   +256  : flag u32[NREP*16]            (memset 0), 512 B
  //   +768  : hbuf u32[NBUF*HD*2]          (memset 0), 32 KB
  //   +32KB+768: xmirror u32[NXCD*NBUF*HD*2] (memset 0), 256 KB
  char* base = (char*)d_ws;
  int*      relay_slot = (int*)base;
  unsigned* flag    = (unsigned*)(base + 256);
  unsigned* hbuf    = (unsigned*)(base + 768);
  unsigned* xmirror = (unsigned*)(base + 768 + NBUF * HD * 2 * sizeof(unsigned));
  size_t zero_bytes = 512 + (NBUF * HD * 2 + NXCD * NBUF * HD * 2) * sizeof(unsigned);

  hipMemsetAsync(base, 0xFF, 256, stream);               // relay_slot = -1
  hipMemsetAsync(base + 256, 0, zero_bytes, stream);     // flags/tags = 0
  hipLaunchKernelGGL(lstm_persistent, dim3(NBLK + 1), dim3(NTHR), 0, stream,
                     x, Wih, Whh, bih, bhh, Wfc, bfc, out,
                     relay_slot, flag, hbuf, xmirror);
}

// Round 11
// 42702.356 us; speedup vs baseline: 1.4549x; 1.4549x over previous
//
#include <hip/hip_runtime.h>

#define TT    8192
#define HD    1024
#define NCB   128       // compute blocks; block cb owns units cb*8 .. cb*8+7
#define NTHR  256
#define NBUF  4         // dense-value ring depth

typedef float f32x4 __attribute__((ext_vector_type(4)));
typedef int   i32x4 __attribute__((ext_vector_type(4)));

// ---- LLC-coherent accesses (sc0 sc1 = bypass L1+L2, coherent at MALL) ----
__device__ __forceinline__ i32x4 llc_load4i(const int* p) {
  i32x4 r;
  asm volatile("global_load_dwordx4 %0, %1, off sc0 sc1\n\ts_waitcnt vmcnt(0)"
               : "=v"(r) : "v"(p) : "memory");
  return r;
}
__device__ __forceinline__ f32x4 llc_load4f(const float* p) {
  f32x4 r;
  asm volatile("global_load_dwordx4 %0, %1, off sc0 sc1\n\ts_waitcnt vmcnt(0)"
               : "=v"(r) : "v"(p) : "memory");
  return r;
}
__device__ __forceinline__ void llc_store1f(float* p, float v) {
  asm volatile("global_store_dword %0, %1, off sc0 sc1" :: "v"(p), "v"(v) : "memory");
}
__device__ __forceinline__ void llc_store1i(int* p, int v) {
  asm volatile("global_store_dword %0, %1, off sc0 sc1" :: "v"(p), "v"(v) : "memory");
}
__device__ __forceinline__ void vm_drain() {
  asm volatile("s_waitcnt vmcnt(0)" ::: "memory");
}

__device__ __forceinline__ float sigf(float z) {
  return 1.0f / (1.0f + __expf(-z));
}
__device__ __forceinline__ float tanh_fast(float z) {
  float az = fabsf(z);
  float e  = __expf(2.0f * az);          // >= 1
  float t  = 1.0f - 2.0f / (e + 1.0f);
  return z < 0.0f ? -t : t;
}

#define FMA4(acc, hvv, wvv)                                      \
  acc = fmaf((hvv).x, (wvv).x, acc);                             \
  acc = fmaf((hvv).y, (wvv).y, acc);                             \
  acc = fmaf((hvv).z, (wvv).z, acc);                             \
  acc = fmaf((hvv).w, (wvv).w, acc);

// vbuf: float[NBUF][HD] dense h ring (slot t%NBUF).  done: int[NCB];
// done[cb] = t+1  <=>  block cb's 8 h-values of step t are ACKED at the MALL
// (per-wave vmcnt(0) drain + block barrier precede the done-store; same
// certified-gate mechanism R7 proved correct).  Consumers read values with
// NO verification.
//
// RING SAFETY (NBUF=4): producer P stores h_{t+3} (slot (t-1)%4) only after
// its gate saw done[*] >= t+3, i.e. every block produced h_{t+2}, which
// required its certified read of h_{t+1}, which required done >= t+2, ...
// inductively every block's read of h_t's source slot completed.  QED.
extern "C" __global__ __launch_bounds__(NTHR, 1)
void lstm_persistent(const float* __restrict__ x,
                     const float* __restrict__ W_ih,
                     const float* __restrict__ W_hh,
                     const float* __restrict__ b_ih,
                     const float* __restrict__ b_hh,
                     const float* __restrict__ W_fc,
                     const float* __restrict__ b_fc,
                     float* __restrict__ out,
                     int*   __restrict__ done,
                     float* __restrict__ vbuf)
{
  __shared__ float x_lds[TT];     // 32 KB: whole input sequence
  __shared__ float h_lds[HD];     //  4 KB: broadcast of h_{t-1}

  const int tid   = threadIdx.x;
  const int wave  = tid >> 6;     // 0..3
  const int lane  = tid & 63;
  const int g     = lane >> 4;    // gate 0..3 (i,f,g,o)
  const int kc    = lane & 15;    // k-chunk within the 1024-dot
  const int cb    = blockIdx.x;   // 0..127
  const int ubase = cb * 8 + wave * 2;    // this wave's 2 hidden units

  // ---- one-time staging -------------------------------------------------
  for (int i = tid; i < TT / 4; i += NTHR)
    ((float4*)x_lds)[i] = ((const float4*)x)[i];

  // W_hh rows (gate g, units ubase+0/1) — lane covers k = m*64 + kc*4 + 0..3
  float4 w4[2][16];
#pragma unroll
  for (int j = 0; j < 2; ++j) {
    const float* wr = W_hh + (size_t)(g * HD + ubase + j) * HD + kc * 4;
#pragma unroll
    for (int m = 0; m < 16; ++m)
      w4[j][m] = *((const float4*)(wr + m * 64));
  }
  float4 wfc4[4];
#pragma unroll
  for (int m = 0; m < 4; ++m)
    wfc4[m] = *((const float4*)(W_fc + m * 256 + lane * 4));
  const float bfc_val = b_fc[0];

  // lanes 0,1 own units ubase+lane
  float wih_g[4], bs_g[4];
  {
    const int ul = ubase + (lane & 1);
#pragma unroll
    for (int q = 0; q < 4; ++q) {
      int r = q * HD + ul;
      wih_g[q] = W_ih[r];
      bs_g[q]  = b_ih[r] + b_hh[r];
    }
  }
  float c_state = 0.0f;
  __syncthreads();                // x_lds ready

  const int* done_mine = done + ((lane & 31) << 2);   // 32 lanes cover 128 words

  // ---- the sequential scan ---------------------------------------------
  for (int t = 0; t < TT; ++t) {
    const bool doproj = (t > 0) && (wave == 1) && (cb == (t & 127));
    float acc0 = 0.f, acc1 = 0.f;
    float4 hp4[4];

    if (t > 0) {
      // certified gate: poll all 128 done words (8 lines; all waves poll)
      for (;;) {
        i32x4 d = llc_load4i(done_mine);
        if (__all(d.x >= t && d.y >= t && d.z >= t && d.w >= t)) break;
      }
      // certified dense read: 16 B/thread, 4 KB/block, 0.5 MB chip-wide
      f32x4 hv = llc_load4f(vbuf + ((t - 1) & (NBUF - 1)) * HD + tid * 4);
      ((f32x4*)h_lds)[tid] = hv;
      __syncthreads();

      // 2 units x 64 FMAs; h fragments reused across the two units
      const float* hp = h_lds + kc * 4;
#pragma unroll
      for (int m = 0; m < 16; ++m) {
        float4 hm = *((const float4*)(hp + m * 64));
        FMA4(acc0, hm, w4[0][m]);
        FMA4(acc1, hm, w4[1][m]);
      }

      if (doproj) {
#pragma unroll
        for (int m = 0; m < 4; ++m)
          hp4[m] = *((const float4*)(h_lds + m * 256 + lane * 4));
      }
    }

    // butterfly within each 16-lane gate-group (4 rounds, 2 accs)
#pragma unroll
    for (int s = 1; s < 16; s <<= 1) {
      acc0 += __shfl_xor(acc0, s);
      acc1 += __shfl_xor(acc1, s);
    }
    // broadcast gate sums; lanes 0,1 take their unit's four
    float gi0 = __shfl(acc0, 0),  gf0 = __shfl(acc0, 16);
    float gg0 = __shfl(acc0, 32), go0 = __shfl(acc0, 48);
    float gi1 = __shfl(acc1, 0),  gf1 = __shfl(acc1, 16);
    float gg1 = __shfl(acc1, 32), go1 = __shfl(acc1, 48);

    if (lane < 2) {
      float gi = lane ? gi1 : gi0, gf = lane ? gf1 : gf0;
      float gg = lane ? gg1 : gg0, go = lane ? go1 : go0;
      float xt = x_lds[t];
      gi += fmaf(xt, wih_g[0], bs_g[0]);
      gf += fmaf(xt, wih_g[1], bs_g[1]);
      gg += fmaf(xt, wih_g[2], bs_g[2]);
      go += fmaf(xt, wih_g[3], bs_g[3]);
      c_state  = sigf(gf) * c_state + sigf(gi) * tanh_fast(gg);
      float hn = sigf(go) * tanh_fast(c_state);
      llc_store1f(vbuf + (t & (NBUF - 1)) * HD + ubase + lane, hn);
    }
    vm_drain();                   // this wave's h-stores ACKED at MALL
    __syncthreads();              // => all 8 of this block's stores ACKED
    if (tid == 0)
      llc_store1i(done + cb, t + 1);     // certificate, fire & forget

    // fused output projection for step t-1 (register-only, off crit path)
    if (doproj) {
      float p = 0.f;
#pragma unroll
      for (int m = 0; m < 4; ++m) { FMA4(p, hp4[m], wfc4[m]); }
#pragma unroll
      for (int s = 1; s < 64; s <<= 1) p += __shfl_xor(p, s);
      if (lane == 0) out[t - 1] = p + bfc_val;
    }
  }

  // ---- epilogue: out[TT-1] by block 0 -----------------------------------
  if (cb == 0) {
    for (;;) {
      i32x4 d = llc_load4i(done_mine);
      if (__all(d.x >= TT && d.y >= TT && d.z >= TT && d.w >= TT)) break;
    }
    f32x4 hv = llc_load4f(vbuf + ((TT - 1) & (NBUF - 1)) * HD + tid * 4);
    ((f32x4*)h_lds)[tid] = hv;
    __syncthreads();
    if (wave == 1) {
      float p = 0.f;
#pragma unroll
      for (int m = 0; m < 4; ++m) {
        float4 hm = *((const float4*)(h_lds + m * 256 + lane * 4));
        FMA4(p, hm, wfc4[m]);
      }
#pragma unroll
      for (int s = 1; s < 64; s <<= 1) p += __shfl_xor(p, s);
      if (lane == 0) out[TT - 1] = p + bfc_val;
    }
  }
}

extern "C" void kernel_launch(void* const* d_in, const int* in_sizes, int n_in,
                              void* d_out, int out_size, void* d_ws, size_t ws_size,
                              hipStream_t stream) {
  const float* x   = (const float*)d_in[0];
  const float* Wih = (const float*)d_in[1];
  const float* Whh = (const float*)d_in[2];
  const float* bih = (const float*)d_in[3];
  const float* bhh = (const float*)d_in[4];
  const float* Wfc = (const float*)d_in[5];
  const float* bfc = (const float*)d_in[6];
  float* out = (float*)d_out;

  // ws layout: [done: NCB int = 512 B][vbuf: NBUF*HD floats = 16 KB]
  int*   done = (int*)d_ws;
  float* vbuf = (float*)((char*)d_ws + NCB * sizeof(int));

  // zero done (0 < any t); vbuf is always certified-written before read
  hipMemsetAsync(d_ws, 0, NCB * sizeof(int), stream);
  hipLaunchKernelGGL(lstm_persistent, dim3(NCB), dim3(NTHR), 0, stream,
                     x, Wih, Whh, bih, bhh, Wfc, bfc, out, done, vbuf);
}

// Round 12
// 25432.433 us; speedup vs baseline: 2.4429x; 1.6791x over previous
//
#include <hip/hip_runtime.h>

#define TT    8192
#define HD    1024
#define NBLK  256
#define NTHR  256
#define NBUF  4         // ring depth — safety proof below
#define NDR   8         // data replicas (one per XCD-aligned reader set)
#define RSTRIDE (NBUF * HD * 2)   // u32 stride between replicas

typedef int i32x4 __attribute__((ext_vector_type(4)));
typedef int i32x2 __attribute__((ext_vector_type(2)));

// ---- LLC-coherent accesses (sc0 sc1 = coherent at the fabric/MALL) ----
__device__ __forceinline__ void llc_load_pair(const unsigned* p, i32x4& a, i32x4& b) {
  asm volatile("global_load_dwordx4 %0, %2, off sc0 sc1\n\t"
               "global_load_dwordx4 %1, %3, off sc0 sc1\n\t"
               "s_waitcnt vmcnt(0)"
               : "=&v"(a), "=&v"(b)
               : "v"(p), "v"(p + 4)
               : "memory");
}
__device__ __forceinline__ void llc_store2(unsigned* p, unsigned lo, unsigned hi) {
  i32x2 v; v.x = (int)lo; v.y = (int)hi;
  asm volatile("global_store_dwordx2 %0, %1, off sc0 sc1"
               :: "v"(p), "v"(v) : "memory");
}

__device__ __forceinline__ float sigf(float z) {
  return 1.0f / (1.0f + __expf(-z));
}
__device__ __forceinline__ float tanh_fast(float z) {
  float az = fabsf(z);
  float e  = __expf(2.0f * az);          // >= 1
  float t  = 1.0f - 2.0f / (e + 1.0f);
  return z < 0.0f ? -t : t;
}

#define FMA4(acc, hvv, wvv)                                      \
  acc = fmaf((hvv).x, (wvv).x, acc);                             \
  acc = fmaf((hvv).y, (wvv).y, acc);                             \
  acc = fmaf((hvv).z, (wvv).z, acc);                             \
  acc = fmaf((hvv).w, (wvv).w, acc);

// hbufR: unsigned[NDR][NBUF][HD][2] {value_bits, tag}; h of step t -> slot
// t%NBUF, tag t+1, stored by its producer to ALL NDR replicas (8-B atomic
// pair: tag certifies value).  Consumer block b tag-polls ONLY replica b&7
// (32 B/thread).  Per replica: 32 blocks x 4 waves x 2 tx = 256 tx/round
// over 128 lines = ~2 tx/line/round — far below the congestion regime that
// sank the single-copy direct poll (R3: 16 tx/line/round).
//
// RING SAFETY (NBUF=4, all replicas): block R stores h_{t+4} (overwriting
// slot t%4 in every replica) only after verifying its replica of h_{t+3};
// h_{t+3} exists only if every block finished step t+3, hence verified its
// replica of h_{t+2}; ... hence every block finished step t+1, i.e. EVERY
// block (each on its own replica) completed its verified read of slot t%4.
// 3 steps of slack, quantified over all readers of all replicas.  Tag-==
// polling therefore can never see a slot skip its expected tag.  QED.
extern "C" __global__ __launch_bounds__(NTHR, 1)
void lstm_persistent(const float* __restrict__ x,
                     const float* __restrict__ W_ih,
                     const float* __restrict__ W_hh,
                     const float* __restrict__ b_ih,
                     const float* __restrict__ b_hh,
                     const float* __restrict__ W_fc,
                     const float* __restrict__ b_fc,
                     float* __restrict__ out,
                     unsigned* __restrict__ hbufR)
{
  __shared__ float x_lds[TT];     // 32 KB: whole input sequence
  __shared__ float h_lds[HD];     //  4 KB: broadcast of h_{t-1}

  const int tid  = threadIdx.x;
  const int wave = tid >> 6;
  const int lane = tid & 63;
  const int g    = lane >> 4;     // gate 0..3 (i,f,g,o)
  const int kc   = lane & 15;     // k-chunk within the 1024-dot
  const int blk  = blockIdx.x;
  const int unit = blk * 4 + wave;
  const unsigned myrep = (unsigned)(blk & (NDR - 1));   // XCD-aligned replica

  // ---- one-time staging -------------------------------------------------
  for (int i = tid; i < TT / 4; i += NTHR)
    ((float4*)x_lds)[i] = ((const float4*)x)[i];

  // W_hh row (gate g, unit) — lane covers k = m*64 + kc*4 + {0..3}
  float4 w4[16];
  {
    const float* wr = W_hh + (size_t)(g * HD + unit) * HD + kc * 4;
#pragma unroll
    for (int m = 0; m < 16; ++m)
      w4[m] = *((const float4*)(wr + m * 64));
  }
  float4 wfc4[4];
#pragma unroll
  for (int m = 0; m < 4; ++m)
    wfc4[m] = *((const float4*)(W_fc + m * 256 + lane * 4));
  const float bfc_val = b_fc[0];

  float wih_g[4], bs_g[4];
#pragma unroll
  for (int q = 0; q < 4; ++q) {
    int r = q * HD + unit;
    wih_g[q] = W_ih[r];
    bs_g[q]  = b_ih[r] + b_hh[r];
  }
  float c_state = 0.0f;
  __syncthreads();                // x_lds ready

  // ---- the sequential scan: ONE fabric hop per step ---------------------
  for (int t = 0; t < TT; ++t) {
    const bool doproj = (t > 0) && (wave == 1) && (blk == (t & 255));
    float accs = 0.0f;
    float4 hp4[4];

    if (t > 0) {
      const int slot = (t - 1) & (NBUF - 1);
      // direct tag-poll of own replica: own 4 pairs (32 B) until tags == t
      const unsigned* src =
          hbufR + myrep * RSTRIDE + ((size_t)slot * HD + tid * 4) * 2;
      i32x4 A, B;
      do {
        llc_load_pair(src, A, B);
      } while (!(A.y == t && A.w == t && B.y == t && B.w == t));
      float4 hv;
      hv.x = __int_as_float(A.x); hv.y = __int_as_float(A.z);
      hv.z = __int_as_float(B.x); hv.w = __int_as_float(B.z);
      ((float4*)h_lds)[tid] = hv;
      __syncthreads();

      // fragments + 64 FMAs (4 independent sub-chains)
      const float* hp = h_lds + kc * 4;
      float s0 = 0.f, s1 = 0.f, s2 = 0.f, s3 = 0.f;
#pragma unroll
      for (int mb = 0; mb < 4; ++mb) {
        float4 ha = *((const float4*)(hp + (mb * 4 + 0) * 64));
        float4 hb = *((const float4*)(hp + (mb * 4 + 1) * 64));
        float4 hc = *((const float4*)(hp + (mb * 4 + 2) * 64));
        float4 hd = *((const float4*)(hp + (mb * 4 + 3) * 64));
        FMA4(s0, ha, w4[mb * 4 + 0]);
        FMA4(s1, hb, w4[mb * 4 + 1]);
        FMA4(s2, hc, w4[mb * 4 + 2]);
        FMA4(s3, hd, w4[mb * 4 + 3]);
      }
      accs = (s0 + s1) + (s2 + s3);

      if (doproj) {
#pragma unroll
        for (int m = 0; m < 4; ++m)
          hp4[m] = *((const float4*)(h_lds + m * 256 + lane * 4));
      }
    }

    // 4-round butterfly over kc: every lane in a gate-group gets the row sum
#pragma unroll
    for (int s = 1; s < 16; s <<= 1)
      accs += __shfl_xor(accs, s);

    float gi = __shfl(accs, 0);
    float gf = __shfl(accs, 16);
    float gg = __shfl(accs, 32);
    float go = __shfl(accs, 48);

    if (lane == 0) {
      float xt = x_lds[t];
      gi += fmaf(xt, wih_g[0], bs_g[0]);
      gf += fmaf(xt, wih_g[1], bs_g[1]);
      gg += fmaf(xt, wih_g[2], bs_g[2]);
      go += fmaf(xt, wih_g[3], bs_g[3]);
      c_state  = sigf(gf) * c_state + sigf(gi) * tanh_fast(gg);
      float hn = sigf(go) * tanh_fast(c_state);
      // broadcast the tagged pair to all NDR replicas (fire & forget)
      unsigned vv = __float_as_uint(hn), tg = (unsigned)(t + 1);
      unsigned* pb = hbufR + ((size_t)(t & (NBUF - 1)) * HD + unit) * 2;
#pragma unroll
      for (int r = 0; r < NDR; ++r)
        llc_store2(pb + r * RSTRIDE, vv, tg);
    }

    // fused output projection for step t-1 (register-only, off crit path)
    if (doproj) {
      float p = 0.f;
#pragma unroll
      for (int m = 0; m < 4; ++m) { FMA4(p, hp4[m], wfc4[m]); }
#pragma unroll
      for (int s = 1; s < 64; s <<= 1) p += __shfl_xor(p, s);
      if (lane == 0) out[t - 1] = p + bfc_val;
    }
  }

  // ---- epilogue: out[TT-1] by block 0 (replica 0, tag-verified) ----------
  if (blk == 0) {
    const unsigned* src =
        hbufR + (((size_t)((TT - 1) & (NBUF - 1)) * HD + tid * 4) * 2);
    i32x4 A, B;
    do {
      llc_load_pair(src, A, B);
    } while (!(A.y == TT && A.w == TT && B.y == TT && B.w == TT));
    float4 hv;
    hv.x = __int_as_float(A.x); hv.y = __int_as_float(A.z);
    hv.z = __int_as_float(B.x); hv.w = __int_as_float(B.z);
    ((float4*)h_lds)[tid] = hv;
    __syncthreads();
    if (wave == 1) {
      float p = 0.f;
#pragma unroll
      for (int m = 0; m < 4; ++m) {
        float4 hm = *((const float4*)(h_lds + m * 256 + lane * 4));
        FMA4(p, hm, wfc4[m]);
      }
#pragma unroll
      for (int s = 1; s < 64; s <<= 1) p += __shfl_xor(p, s);
      if (lane == 0) out[TT - 1] = p + bfc_val;
    }
  }
}

extern "C" void kernel_launch(void* const* d_in, const int* in_sizes, int n_in,
                              void* d_out, int out_size, void* d_ws, size_t ws_size,
                              hipStream_t stream) {
  const float* x   = (const float*)d_in[0];
  const float* Wih = (const float*)d_in[1];
  const float* Whh = (const float*)d_in[2];
  const float* bih = (const float*)d_in[3];
  const float* bhh = (const float*)d_in[4];
  const float* Wfc = (const float*)d_in[5];
  const float* bfc = (const float*)d_in[6];
  float* out = (float*)d_out;

  // ws: hbufR u32[NDR][NBUF][HD][2] = 256 KB, tags zeroed (0 != any tag >= 1)
  unsigned* hbufR = (unsigned*)d_ws;
  hipMemsetAsync(d_ws, 0, (size_t)NDR * RSTRIDE * sizeof(unsigned), stream);
  hipLaunchKernelGGL(lstm_persistent, dim3(NBLK), dim3(NTHR), 0, stream,
                     x, Wih, Whh, bih, bhh, Wfc, bfc, out, hbufR);
}